// Round 3
// baseline (274.076 us; speedup 1.0000x reference)
//
#include <hip/hip_runtime.h>
#include <math.h>

#define S_LEN 2048
#define HIDN  2048
#define NH    32
#define NKV   8
#define HD    64
#define KVW   (NKV * HD)     // 512
#define CTX   (S_LEN - 10)   // 2038: rows < CTX use boost rope, rows >= CTX use narrow

typedef unsigned short u16;
typedef __attribute__((ext_vector_type(4))) float f32x4;
typedef __attribute__((ext_vector_type(16))) float f32x16;
typedef __attribute__((ext_vector_type(8))) short s16x8;

#define QSCL 0.18033688011112042f    // 0.125 * log2(e): attn uses exp2(score)
#define L2_1E4 13.287712379549449f   // log2(10000)

__device__ __forceinline__ float bf2f(u16 u) {
  union { unsigned int i; float f; } v; v.i = ((unsigned int)u) << 16; return v.f;
}
__device__ __forceinline__ u16 f2bf(float f) {
  union { float f; unsigned int i; } v; v.f = f;
  unsigned int r = v.i + 0x7fffu + ((v.i >> 16) & 1u);
  return (u16)(r >> 16);
}
__device__ __forceinline__ unsigned int cvt_pk_bf16(float a, float b) {
  unsigned int d;
  asm("v_cvt_pk_bf16_f32 %0, %1, %2" : "=v"(d) : "v"(a), "v"(b));
  return d;
}

// ---------------------------------------------------------------------------
// fp32 -> bf16 conversion: hidden + Wq + Wk + Wv + Wo in one launch.
// ---------------------------------------------------------------------------
__global__ __launch_bounds__(256) void conv_all(
    const float* __restrict__ h,  const float* __restrict__ wq,
    const float* __restrict__ wk, const float* __restrict__ wv,
    const float* __restrict__ wo,
    u16* __restrict__ Hb, u16* __restrict__ Wqb, u16* __restrict__ Wkb,
    u16* __restrict__ Wvb, u16* __restrict__ Wob)
{
  const int i = blockIdx.x * 256 + threadIdx.x;   // one float4 per thread
  const float* src; u16* dst; int off;
  if      (i < 1048576) { src = h;  dst = Hb;  off = i; }
  else if (i < 2097152) { src = wq; dst = Wqb; off = i - 1048576; }
  else if (i < 2359296) { src = wk; dst = Wkb; off = i - 2097152; }
  else if (i < 2621440) { src = wv; dst = Wvb; off = i - 2359296; }
  else                  { src = wo; dst = Wob; off = i - 2621440; }
  const float4 f4 = ((const float4*)src)[off];
  ushort4 o4;
  o4.x = f2bf(f4.x); o4.y = f2bf(f4.y); o4.z = f2bf(f4.z); o4.w = f2bf(f4.w);
  ((ushort4*)dst)[off] = o4;
}

// ---------------------------------------------------------------------------
// GEMM: C[M,N] = A[M,K] * B[N,K]^T (bf16 in, fp32 accum), 128x128 tile, BK=64.
// Explicit LDS double-buffer + counted vmcnt (never 0 in steady state): at
// 1 block/CU the old __syncthreads() vmcnt(0) drain was fully exposed each
// K-step; raw s_barrier + vmcnt(8) keeps next-tile loads in flight across
// the whole MFMA phase (T3/T4 minimum form).
// MODE: 0 = Q (rope boost/narrow + QSCL, bf16)
//       1 = K (rope dual: boost -> Cv, narrow -> Cv2, bf16)
//       2 = V (write C^T, row stride S_LEN, bf16)
//       3 = OUT (f32)
// ---------------------------------------------------------------------------
#define BM 128
#define BN 128
#define BK 64

template<int MODE>
__device__ __forceinline__ void gemm_body(
    u16* __restrict__ As, u16* __restrict__ Bs,       // each 2*BM*BK (dbuf)
    const u16* __restrict__ A, const u16* __restrict__ B,
    void* __restrict__ Cv, void* __restrict__ Cv2,
    int N, int K, int row0, int col0, const int* __restrict__ pos)
{
  const int tid  = threadIdx.x;
  const int wave = tid >> 6;
  const int lane = tid & 63;
  const int wr = (wave >> 1) * 64;
  const int wc = (wave & 1) * 64;

  f32x4 acc[4][4] = {};

  const int srow = wave * 8 + (lane >> 3);
  const int scol = (lane & 7) * 8;
  const int NT = K / BK;

  // prologue: issue tile 0 into buffer 0
#pragma unroll
  for (int it = 0; it < 4; ++it) {
    const u16* gA = A + (size_t)(row0 + it * 32 + srow) * K + scol;
    const u16* gB = B + (size_t)(col0 + it * 32 + srow) * K + scol;
    u16* lA = As + (it * 32 + wave * 8) * BK;
    u16* lB = Bs + (it * 32 + wave * 8) * BK;
    __builtin_amdgcn_global_load_lds((const __attribute__((address_space(1))) void*)gA,
                                     (__attribute__((address_space(3))) void*)lA, 16, 0, 0);
    __builtin_amdgcn_global_load_lds((const __attribute__((address_space(1))) void*)gB,
                                     (__attribute__((address_space(3))) void*)lB, 16, 0, 0);
  }

  int cur = 0;
  for (int t = 0; t < NT; ++t) {
    // B1: all waves finished reading buf[cur^1] (tile t-1) -> safe to overwrite
    __builtin_amdgcn_s_barrier();
    __builtin_amdgcn_sched_barrier(0);
    if (t + 1 < NT) {
      const int kt = (t + 1) * BK;
      const int nx = (cur ^ 1) * (BM * BK);
#pragma unroll
      for (int it = 0; it < 4; ++it) {
        const u16* gA = A + (size_t)(row0 + it * 32 + srow) * K + kt + scol;
        const u16* gB = B + (size_t)(col0 + it * 32 + srow) * K + kt + scol;
        u16* lA = As + nx + (it * 32 + wave * 8) * BK;
        u16* lB = Bs + nx + (it * 32 + wave * 8) * BK;
        __builtin_amdgcn_global_load_lds((const __attribute__((address_space(1))) void*)gA,
                                         (__attribute__((address_space(3))) void*)lA, 16, 0, 0);
        __builtin_amdgcn_global_load_lds((const __attribute__((address_space(1))) void*)gB,
                                         (__attribute__((address_space(3))) void*)lB, 16, 0, 0);
      }
      // wait for tile t's 8 loads (issued last iter); the 8 just-issued stay in flight
      asm volatile("s_waitcnt vmcnt(8)" ::: "memory");
    } else {
      asm volatile("s_waitcnt vmcnt(0)" ::: "memory");
    }
    __builtin_amdgcn_sched_barrier(0);
    // B2: tile t resident for ALL waves
    __builtin_amdgcn_s_barrier();
    __builtin_amdgcn_sched_barrier(0);

    const u16* Asb = As + cur * (BM * BK);
    const u16* Bsb = Bs + cur * (BM * BK);
#pragma unroll
    for (int kk = 0; kk < 2; ++kk) {
      const int ko = kk * 32 + (lane >> 4) * 8;
      s16x8 af[4], bg[4];
#pragma unroll
      for (int mi = 0; mi < 4; ++mi)
        af[mi] = *(const s16x8*)&Asb[(wr + mi * 16 + (lane & 15)) * BK + ko];
#pragma unroll
      for (int ni = 0; ni < 4; ++ni)
        bg[ni] = *(const s16x8*)&Bsb[(wc + ni * 16 + (lane & 15)) * BK + ko];
#pragma unroll
      for (int mi = 0; mi < 4; ++mi)
#pragma unroll
        for (int ni = 0; ni < 4; ++ni)
          acc[mi][ni] = __builtin_amdgcn_mfma_f32_16x16x32_bf16(af[mi], bg[ni], acc[mi][ni], 0, 0, 0);
    }
    cur ^= 1;
  }

  const int rq = (lane >> 4) * 4;
  const int cq = lane & 15;

  if (MODE == 3) {
#pragma unroll
    for (int mi = 0; mi < 4; ++mi)
#pragma unroll
      for (int ni = 0; ni < 4; ++ni) {
        const int r = row0 + wr + mi * 16 + rq;
        const int c = col0 + wc + ni * 16 + cq;
#pragma unroll
        for (int t = 0; t < 4; ++t)
          ((float*)Cv)[(size_t)(r + t) * N + c] = acc[mi][ni][t];
      }
  } else if (MODE == 2) {
#pragma unroll
    for (int mi = 0; mi < 4; ++mi)
#pragma unroll
      for (int ni = 0; ni < 4; ++ni) {
        const int r = row0 + wr + mi * 16 + rq;
        const int c = col0 + wc + ni * 16 + cq;
        ushort4 o4;
        o4.x = f2bf(acc[mi][ni][0]); o4.y = f2bf(acc[mi][ni][1]);
        o4.z = f2bf(acc[mi][ni][2]); o4.w = f2bf(acc[mi][ni][3]);
        *(ushort4*)&((u16*)Cv)[(size_t)c * S_LEN + r] = o4;
      }
  } else {
    // MODE 0/1: fused rope. Thread owns cols c (d=ni*16+cq<32, ni in {0,1})
    // and c+32 (ni+2) -> rotate-half pair is thread-local. Applied to f32 acc
    // before the single bf16 round (more precise than the old 2-round path).
#pragma unroll
    for (int mi = 0; mi < 4; ++mi) {
#pragma unroll
      for (int t = 0; t < 4; ++t) {
        const int i = row0 + wr + mi * 16 + rq + t;
        const float fpos = (float)pos[i];
#pragma unroll
        for (int ni = 0; ni < 2; ++ni) {
          const int d = ni * 16 + cq;            // 0..31
          const int c = col0 + wc + ni * 16 + cq;
          const float f = exp2f(-(float)(2 * d) * (1.0f / HD) * L2_1E4);
          const float x1 = acc[mi][ni][t], x2 = acc[mi][ni + 2][t];
          if (MODE == 0) {
            const float scl = (i < CTX) ? 1.0f : 0.25f;
            float sn, cs; sincosf(fpos * scl * f, &sn, &cs);
            u16* Cq = (u16*)Cv;
            Cq[(size_t)i * N + c]      = f2bf((x1 * cs - x2 * sn) * QSCL);
            Cq[(size_t)i * N + c + 32] = f2bf((x2 * cs + x1 * sn) * QSCL);
          } else {
            float sb_, cb_; sincosf(fpos * f, &sb_, &cb_);
            float sn_, cn_; sincosf(fpos * 0.25f * f, &sn_, &cn_);
            u16* Kb_ = (u16*)Cv;
            u16* Kn_ = (u16*)Cv2;
            Kb_[(size_t)i * N + c]      = f2bf(x1 * cb_ - x2 * sb_);
            Kb_[(size_t)i * N + c + 32] = f2bf(x2 * cb_ + x1 * sb_);
            Kn_[(size_t)i * N + c]      = f2bf(x1 * cn_ - x2 * sn_);
            Kn_[(size_t)i * N + c + 32] = f2bf(x2 * cn_ + x1 * sn_);
          }
        }
      }
    }
  }
}

__global__ __launch_bounds__(256) void gemm_qkv(
    const u16* __restrict__ A, const u16* __restrict__ Wq, const u16* __restrict__ Wk,
    const u16* __restrict__ Wv, u16* __restrict__ Q, u16* __restrict__ Kb,
    u16* __restrict__ Kn, u16* __restrict__ Vt, const int* __restrict__ pos)
{
  __shared__ u16 As[2 * BM * BK];
  __shared__ u16 Bs[2 * BN * BK];
  const int bn = blockIdx.x;
  const int row0 = blockIdx.y * BM;
  if (bn < 16)
    gemm_body<0>(As, Bs, A, Wq, Q, nullptr, HIDN, HIDN, row0, bn * BN, pos);
  else if (bn < 20)
    gemm_body<1>(As, Bs, A, Wk, Kb, Kn, KVW, HIDN, row0, (bn - 16) * BN, pos);
  else
    gemm_body<2>(As, Bs, A, Wv, Vt, nullptr, KVW, HIDN, row0, (bn - 20) * BN, pos);
}

__global__ __launch_bounds__(256) void gemm_out(
    const u16* __restrict__ A, const u16* __restrict__ B, float* __restrict__ C, int N, int K)
{
  __shared__ u16 As[2 * BM * BK];
  __shared__ u16 Bs[2 * BN * BK];
  gemm_body<3>(As, Bs, A, B, C, nullptr, N, K, blockIdx.y * BM, blockIdx.x * BN, nullptr);
}

// ---------------------------------------------------------------------------
// MFMA flash attention, 32x32 swapped-QK^T + balanced triangle pairing:
//  - grid 16 x NH; block p runs two 64-row q-tile phases {31-p, p}
//    -> exactly 33 key-tile iters per block (load-balanced).
//  - 4 waves split 2x2 over (row-half x key-half): each wave computes a
//    32x32 score block per 64-key tile via swapped QK^T = mfma(K,Q):
//    lane owns one q-row (col l31), softmax fully lane-local.
//  - P -> PV A-frag in registers via v_cvt_pk_bf16_f32 + v_permlane32_swap
//    (no P LDS round-trip).
//  - key-split requires one cross-wave O/lsum merge per phase through a
//    16KB LDS buffer (stride-1, conflict-free; 2x per block, negligible).
// ---------------------------------------------------------------------------
#define PAD 8
__global__ __launch_bounds__(256) void attn_mfma(
    const u16* __restrict__ Q, const u16* __restrict__ K, const u16* __restrict__ Kn,
    const u16* __restrict__ Vt, u16* __restrict__ O)
{
  __shared__ __align__(16) u16 Ks[64][HD + PAD];
  __shared__ __align__(16) u16 Kns[64][HD + PAD];
  __shared__ __align__(16) u16 Vts[HD][64 + PAD];
  __shared__ __align__(16) float Of[64][64];   // cross-wave O merge
  __shared__ float Lf[2][32];                  // cross-wave lsum merge
  __shared__ float Li[2][32];                  // per-row 1/l broadcast

  const int tid  = threadIdx.x;
  const int wave = tid >> 6;
  const int lane = tid & 63;
  const int l31  = lane & 31;
  const int hi   = lane >> 5;
  const int wr   = wave >> 1;                  // row half (0,1)
  const int wk   = wave & 1;                   // key half (0,1)
  const int h    = blockIdx.y;
  const int kh   = h >> 2;
  const int pr   = blockIdx.x;                 // pair index 0..15

  // staging map: 2 iters x 256 threads x 16B cover one 64x64 bf16 tile
  int sa[2], sb[2];
#pragma unroll
  for (int it = 0; it < 2; ++it) {
    const int u = it * 256 + tid;
    sa[it] = u >> 3;
    sb[it] = (u & 7) * 8;
  }

  for (int ph = 0; ph < 2; ++ph) {
    const int qt = ph ? pr : 31 - pr;          // heavy tile first
    const int i_base = qt * 64;
    const int rw0 = i_base + wr * 32;          // this wave's 32 q-rows
    const bool mixed_blk = (qt == 31);
    const bool mixed_wv  = mixed_blk && (rw0 + 31 >= CTX);

    // persistent Q B-frags: B[n=q=l31][k=d = i*16 + hi*8 + j]
    s16x8 bq[4];
#pragma unroll
    for (int i = 0; i < 4; ++i)
      bq[i] = *(const s16x8*)(Q + (size_t)(rw0 + l31) * HIDN + h * HD + i * 16 + hi * 8);

    f32x16 acc0 = {};      // O[q][d], d = l31       (rows in reg pattern)
    f32x16 acc1 = {};      // O[q][d], d = l31 + 32
    float lsum = 0.f;      // partial row sum (this lane's 16 keys)

    const int ntiles = qt + 1;
    s16x8 kr[2], vr[2], knr[2];
#pragma unroll
    for (int it = 0; it < 2; ++it) {
      kr[it] = *(const s16x8*)(K  + (size_t)sa[it] * KVW + kh * HD + sb[it]);
      vr[it] = *(const s16x8*)(Vt + (size_t)(kh * HD + sa[it]) * S_LEN + sb[it]);
      if (mixed_blk) knr[it] = *(const s16x8*)(Kn + (size_t)sa[it] * KVW + kh * HD + sb[it]);
    }

    for (int t = 0; t < ntiles; ++t) {
      const int jt = t * 64;
      __syncthreads();                        // LDS free (prev tile's reads done)
#pragma unroll
      for (int it = 0; it < 2; ++it) {
        *(s16x8*)&Ks[sa[it]][sb[it]]  = kr[it];
        *(s16x8*)&Vts[sa[it]][sb[it]] = vr[it];
        if (mixed_blk) *(s16x8*)&Kns[sa[it]][sb[it]] = knr[it];
      }
      __syncthreads();                        // LDS ready
      if (t + 1 < ntiles) {                   // prefetch next tile (overlaps compute)
        const int jn = jt + 64;
#pragma unroll
        for (int it = 0; it < 2; ++it) {
          kr[it] = *(const s16x8*)(K  + (size_t)(jn + sa[it]) * KVW + kh * HD + sb[it]);
          vr[it] = *(const s16x8*)(Vt + (size_t)(kh * HD + sa[it]) * S_LEN + jn + sb[it]);
          if (mixed_blk) knr[it] = *(const s16x8*)(Kn + (size_t)(jn + sa[it]) * KVW + kh * HD + sb[it]);
        }
      }

      const int j0 = jt + wk * 32;            // this wave's 32-key group
      if (j0 > rw0 + 31) continue;            // fully masked for this wave
      const bool needmask = (j0 + 31 > rw0);  // straddles the diagonal

      // swapped QK^T: D[m=key (reg pattern)][n=q (l31)]
      f32x16 sc = {};
#pragma unroll
      for (int i = 0; i < 4; ++i) {
        const s16x8 ak = *(const s16x8*)&Ks[wk * 32 + l31][i * 16 + hi * 8];
        sc = __builtin_amdgcn_mfma_f32_32x32x16_bf16(ak, bq[i], sc, 0, 0, 0);
      }
      if (mixed_wv) {                         // rows straddle CTX: also narrow scores
        f32x16 scn = {};
#pragma unroll
        for (int i = 0; i < 4; ++i) {
          const s16x8 ak = *(const s16x8*)&Kns[wk * 32 + l31][i * 16 + hi * 8];
          scn = __builtin_amdgcn_mfma_f32_32x32x16_bf16(ak, bq[i], scn, 0, 0, 0);
        }
        const bool nar = (rw0 + l31) >= CTX;  // per-lane: q-row selects rope
#pragma unroll
        for (int r = 0; r < 16; ++r) sc[r] = nar ? scn[r] : sc[r];
      }

      // lane-local softmax: p = exp2(min(s,80)) (Q pre-scaled by log2e/8)
      float p[16];
#pragma unroll
      for (int r = 0; r < 16; ++r) {
        float e = __builtin_amdgcn_exp2f(fminf(sc[r], 80.f));
        if (needmask) {
          const int key = j0 + (r & 3) + 8 * (r >> 2) + 4 * hi;
          e = (key > rw0 + l31) ? 0.f : e;
        }
        p[r] = e;
        lsum += e;
      }

      // pack p -> bf16 pairs: c[blk][j] = keys 8*blk + 4*hi + {2j, 2j+1}
      unsigned int c[4][2];
#pragma unroll
      for (int blk = 0; blk < 4; ++blk) {
        c[blk][0] = cvt_pk_bf16(p[4 * blk + 0], p[4 * blk + 1]);
        c[blk][1] = cvt_pk_bf16(p[4 * blk + 2], p[4 * blk + 3]);
      }

      // per 16-key slice s: swap halves -> A-frag words, then 2 PV MFMAs
#pragma unroll
      for (int s = 0; s < 2; ++s) {
        unsigned int w0 = c[2 * s][0], w2 = c[2 * s + 1][0];
        unsigned int w1 = c[2 * s][1], w3 = c[2 * s + 1][1];
        asm("v_permlane32_swap_b32 %0, %1" : "+v"(w0), "+v"(w2));
        asm("v_permlane32_swap_b32 %0, %1" : "+v"(w1), "+v"(w3));
        union { unsigned int u[4]; s16x8 v; } af;
        af.u[0] = w0; af.u[1] = w1; af.u[2] = w2; af.u[3] = w3;
        const int kc = wk * 32 + s * 16 + hi * 8;
        const s16x8 v0 = *(const s16x8*)&Vts[l31][kc];
        const s16x8 v1 = *(const s16x8*)&Vts[32 + l31][kc];
        acc0 = __builtin_amdgcn_mfma_f32_32x32x16_bf16(af.v, v0, acc0, 0, 0, 0);
        acc1 = __builtin_amdgcn_mfma_f32_32x32x16_bf16(af.v, v1, acc1, 0, 0, 0);
      }
    }

    // ---- cross-wave merge over key halves + epilogue (per phase) ----
    lsum += __shfl_xor(lsum, 32, 64);         // combine hi halves: row sum over
                                              // this wave's 32 keys, row = rw0+l31
    __syncthreads();                          // all compute done; LDS tiles free
    if (wk == 1) {
#pragma unroll
      for (int r = 0; r < 16; ++r) {
        const int rl = (r & 3) + 8 * (r >> 2) + 4 * hi;
        Of[wr * 32 + rl][l31]      = acc0[r];
        Of[wr * 32 + rl][l31 + 32] = acc1[r];
      }
      if (hi == 0) Lf[wr][l31] = lsum;
    }
    __syncthreads();
    if (wk == 0) {
      const float tot = lsum + Lf[wr][l31];
      const float inv = 1.0f / fmaxf(tot, 1e-30f);
      if (hi == 0) Li[wr][l31] = inv;         // same-wave write->read (in-order LDS)
#pragma unroll
      for (int r = 0; r < 16; ++r) {
        const int rl = (r & 3) + 8 * (r >> 2) + 4 * hi;
        const float iv = Li[wr][rl];
        const size_t o = (size_t)(rw0 + rl) * HIDN + h * HD + l31;
        O[o]      = f2bf((acc0[r] + Of[wr * 32 + rl][l31])      * iv);
        O[o + 32] = f2bf((acc1[r] + Of[wr * 32 + rl][l31 + 32]) * iv);
      }
    }
  }
}

// ---------------------------------------------------------------------------
extern "C" void kernel_launch(void* const* d_in, const int* in_sizes, int n_in,
                              void* d_out, int out_size, void* d_ws, size_t ws_size,
                              hipStream_t stream)
{
  const float* hidden = (const float*)d_in[0];
  const int* pos      = (const int*)d_in[2];   // d_in[1] mask: pure causal, unused
  const float* Wq = (const float*)d_in[3];
  const float* Wk = (const float*)d_in[4];
  const float* Wv = (const float*)d_in[5];
  const float* Wo = (const float*)d_in[6];
  float* out = (float*)d_out;

  char* ws = (char*)d_ws;
  u16* Qb  = (u16*)(ws);                    // 8 MB  bf16 Q (roped+scaled by gemm)
  u16* Kbb = (u16*)(ws + (8u  << 20));      // 2 MB  bf16 boost K (roped by gemm)
  u16* Knb = (u16*)(ws + (10u << 20));      // 2 MB  bf16 narrow K
  u16* Vtb = (u16*)(ws + (12u << 20));      // 2 MB  bf16 V transposed [kv_col][seq]
  u16* Ab  = (u16*)(ws + (14u << 20));      // 8 MB  bf16 attention output
  u16* Hb  = (u16*)(ws + (22u << 20));      // 8 MB  bf16 hidden
  u16* Wqb = (u16*)(ws + (30u << 20));      // 8 MB  bf16 Wq
  u16* Wkb = (u16*)(ws + (38u << 20));      // 2 MB  bf16 Wk
  u16* Wvb = (u16*)(ws + (40u << 20));      // 2 MB  bf16 Wv
  u16* Wob = (u16*)(ws + (42u << 20));      // 8 MB  bf16 Wo  => 50 MB total

  conv_all<<<dim3(14336), 256, 0, stream>>>(hidden, Wq, Wk, Wv, Wo, Hb, Wqb, Wkb, Wvb, Wob);
  gemm_qkv<<<dim3(24, 16), 256, 0, stream>>>(Hb, Wqb, Wkb, Wvb, Qb, Kbb, Knb, Vtb, pos);
  attn_mfma<<<dim3(16, NH), 256, 0, stream>>>(Qb, Kbb, Knb, Vtb, Ab);
  gemm_out<<<dim3(16, 16), 256, 0, stream>>>(Ab, Wob, out, HIDN, HIDN);
}

// Round 4
// 250.253 us; speedup vs baseline: 1.0952x; 1.0952x over previous
//
#include <hip/hip_runtime.h>
#include <math.h>

#define S_LEN 2048
#define HIDN  2048
#define NH    32
#define NKV   8
#define HD    64
#define KVW   (NKV * HD)     // 512
#define CTX   (S_LEN - 10)   // 2038: rows < CTX use boost rope, rows >= CTX use narrow

typedef unsigned short u16;
typedef __attribute__((ext_vector_type(4))) float f32x4;
typedef __attribute__((ext_vector_type(16))) float f32x16;
typedef __attribute__((ext_vector_type(8))) short s16x8;

#define QSCL 0.18033688011112042f    // 0.125 * log2(e): attn uses exp2(score)
#define L2_1E4 13.287712379549449f   // log2(10000)

__device__ __forceinline__ float bf2f(u16 u) {
  union { unsigned int i; float f; } v; v.i = ((unsigned int)u) << 16; return v.f;
}
__device__ __forceinline__ u16 f2bf(float f) {
  union { float f; unsigned int i; } v; v.f = f;
  unsigned int r = v.i + 0x7fffu + ((v.i >> 16) & 1u);
  return (u16)(r >> 16);
}
__device__ __forceinline__ unsigned int cvt_pk_bf16(float a, float b) {
  unsigned int d;
  asm("v_cvt_pk_bf16_f32 %0, %1, %2" : "=v"(d) : "v"(a), "v"(b));
  return d;
}

// ---------------------------------------------------------------------------
// fp32 -> bf16 conversion: hidden + Wq + Wk + Wv + Wo in one launch.
// ---------------------------------------------------------------------------
__global__ __launch_bounds__(256) void conv_all(
    const float* __restrict__ h,  const float* __restrict__ wq,
    const float* __restrict__ wk, const float* __restrict__ wv,
    const float* __restrict__ wo,
    u16* __restrict__ Hb, u16* __restrict__ Wqb, u16* __restrict__ Wkb,
    u16* __restrict__ Wvb, u16* __restrict__ Wob)
{
  const int i = blockIdx.x * 256 + threadIdx.x;   // one float4 per thread
  const float* src; u16* dst; int off;
  if      (i < 1048576) { src = h;  dst = Hb;  off = i; }
  else if (i < 2097152) { src = wq; dst = Wqb; off = i - 1048576; }
  else if (i < 2359296) { src = wk; dst = Wkb; off = i - 2097152; }
  else if (i < 2621440) { src = wv; dst = Wvb; off = i - 2359296; }
  else                  { src = wo; dst = Wob; off = i - 2621440; }
  const float4 f4 = ((const float4*)src)[off];
  ushort4 o4;
  o4.x = f2bf(f4.x); o4.y = f2bf(f4.y); o4.z = f2bf(f4.z); o4.w = f2bf(f4.w);
  ((ushort4*)dst)[off] = o4;
}

// ---------------------------------------------------------------------------
// GEMM: C[M,N] = A[M,K] * B[N,K]^T (bf16 in, fp32 accum), 128x64 tile, BK=64.
// Single-buffered m97-style loop (proven round-2 structure; no sched_barrier,
// no dbuf — both measured regressions). 128x64 tile doubles block count vs
// 128x128: gemm_qkv 768 blocks (3/CU), gemm_out 512 (2/CU) -> implicit
// wave-level overlap (m114) covers the barrier drain that 1 block/CU exposed.
// 4 waves split rows (wave tile 32x64), acc[2][4], LDS 24KB.
// MODE: 0 = Q (fused rope boost/narrow + QSCL, bf16)
//       1 = K (fused rope dual: boost -> Cv, narrow -> Cv2, bf16)
//       2 = V (write C^T, row stride S_LEN, bf16)
//       3 = OUT (f32)
// ---------------------------------------------------------------------------
#define BM 128
#define BN 64
#define BK 64

template<int MODE>
__device__ __forceinline__ void gemm_body(
    u16* __restrict__ As, u16* __restrict__ Bs,
    const u16* __restrict__ A, const u16* __restrict__ B,
    void* __restrict__ Cv, void* __restrict__ Cv2,
    int N, int K, int row0, int col0, const int* __restrict__ pos)
{
  const int tid  = threadIdx.x;
  const int wave = tid >> 6;
  const int lane = tid & 63;
  const int l15  = lane & 15;
  const int wr   = wave * 32;          // wave's 32 output rows

  f32x4 acc[2][4] = {};

  const int srow = wave * 8 + (lane >> 3);   // 0..31
  const int scol = (lane & 7) * 8;

  for (int kt = 0; kt < K; kt += BK) {
#pragma unroll
    for (int it = 0; it < 4; ++it) {         // A: 128 rows
      const u16* gA = A + (size_t)(row0 + it * 32 + srow) * K + kt + scol;
      u16* lA = &As[(it * 32 + wave * 8) * BK];
      __builtin_amdgcn_global_load_lds((const __attribute__((address_space(1))) void*)gA,
                                       (__attribute__((address_space(3))) void*)lA, 16, 0, 0);
    }
#pragma unroll
    for (int it = 0; it < 2; ++it) {         // B: 64 rows
      const u16* gB = B + (size_t)(col0 + it * 32 + srow) * K + kt + scol;
      u16* lB = &Bs[(it * 32 + wave * 8) * BK];
      __builtin_amdgcn_global_load_lds((const __attribute__((address_space(1))) void*)gB,
                                       (__attribute__((address_space(3))) void*)lB, 16, 0, 0);
    }
    __syncthreads();                         // implicit vmcnt(0) drain + barrier
#pragma unroll
    for (int kk = 0; kk < 2; ++kk) {
      const int ko = kk * 32 + (lane >> 4) * 8;
      s16x8 af[2], bg[4];
#pragma unroll
      for (int mi = 0; mi < 2; ++mi)
        af[mi] = *(const s16x8*)&As[(wr + mi * 16 + l15) * BK + ko];
#pragma unroll
      for (int ni = 0; ni < 4; ++ni)
        bg[ni] = *(const s16x8*)&Bs[(ni * 16 + l15) * BK + ko];
#pragma unroll
      for (int mi = 0; mi < 2; ++mi)
#pragma unroll
        for (int ni = 0; ni < 4; ++ni)
          acc[mi][ni] = __builtin_amdgcn_mfma_f32_16x16x32_bf16(af[mi], bg[ni], acc[mi][ni], 0, 0, 0);
    }
    __syncthreads();
  }

  const int rq = (lane >> 4) * 4;
  const int cq = l15;

  if (MODE == 3) {
#pragma unroll
    for (int mi = 0; mi < 2; ++mi)
#pragma unroll
      for (int ni = 0; ni < 4; ++ni) {
        const int r = row0 + wr + mi * 16 + rq;
        const int c = col0 + ni * 16 + cq;
#pragma unroll
        for (int t = 0; t < 4; ++t)
          ((float*)Cv)[(size_t)(r + t) * N + c] = acc[mi][ni][t];
      }
  } else if (MODE == 2) {
#pragma unroll
    for (int mi = 0; mi < 2; ++mi)
#pragma unroll
      for (int ni = 0; ni < 4; ++ni) {
        const int r = row0 + wr + mi * 16 + rq;
        const int c = col0 + ni * 16 + cq;
        ushort4 o4;
        o4.x = f2bf(acc[mi][ni][0]); o4.y = f2bf(acc[mi][ni][1]);
        o4.z = f2bf(acc[mi][ni][2]); o4.w = f2bf(acc[mi][ni][3]);
        *(ushort4*)&((u16*)Cv)[(size_t)c * S_LEN + r] = o4;
      }
  } else {
    // MODE 0/1: fused rope. col0 is head-aligned (64): d = ni*16+cq (<32) pairs
    // with d+32 = cols of (mi, ni+2) -> rotate-half pair is thread-local.
    // Fast __sinf/__cosf: reduction err ~2e-4 rad at pos<=2047, << bf16 round.
#pragma unroll
    for (int mi = 0; mi < 2; ++mi) {
#pragma unroll
      for (int t = 0; t < 4; ++t) {
        const int i = row0 + wr + mi * 16 + rq + t;
        const float fpos = (float)pos[i];
#pragma unroll
        for (int ni = 0; ni < 2; ++ni) {
          const int d = ni * 16 + cq;            // 0..31
          const int c = col0 + d;
          const float f = exp2f(-(float)(2 * d) * (1.0f / HD) * L2_1E4);
          const float x1 = acc[mi][ni][t], x2 = acc[mi][ni + 2][t];
          if (MODE == 0) {
            const float scl = (i < CTX) ? 1.0f : 0.25f;
            const float a  = fpos * scl * f;
            const float cs = __cosf(a), sn = __sinf(a);
            u16* Cq = (u16*)Cv;
            Cq[(size_t)i * N + c]      = f2bf((x1 * cs - x2 * sn) * QSCL);
            Cq[(size_t)i * N + c + 32] = f2bf((x2 * cs + x1 * sn) * QSCL);
          } else {
            const float ab = fpos * f, an = fpos * 0.25f * f;
            const float cb_ = __cosf(ab), sb_ = __sinf(ab);
            const float cn_ = __cosf(an), sn_ = __sinf(an);
            ((u16*)Cv)[(size_t)i * N + c]       = f2bf(x1 * cb_ - x2 * sb_);
            ((u16*)Cv)[(size_t)i * N + c + 32]  = f2bf(x2 * cb_ + x1 * sb_);
            ((u16*)Cv2)[(size_t)i * N + c]      = f2bf(x1 * cn_ - x2 * sn_);
            ((u16*)Cv2)[(size_t)i * N + c + 32] = f2bf(x2 * cn_ + x1 * sn_);
          }
        }
      }
    }
  }
}

__global__ __launch_bounds__(256) void gemm_qkv(
    const u16* __restrict__ A, const u16* __restrict__ Wq, const u16* __restrict__ Wk,
    const u16* __restrict__ Wv, u16* __restrict__ Q, u16* __restrict__ Kb,
    u16* __restrict__ Kn, u16* __restrict__ Vt, const int* __restrict__ pos)
{
  __shared__ u16 As[BM * BK];
  __shared__ u16 Bs[BN * BK];
  const int bn = blockIdx.x;
  const int row0 = blockIdx.y * BM;
  if (bn < 32)
    gemm_body<0>(As, Bs, A, Wq, Q, nullptr, HIDN, HIDN, row0, bn * BN, pos);
  else if (bn < 40)
    gemm_body<1>(As, Bs, A, Wk, Kb, Kn, KVW, HIDN, row0, (bn - 32) * BN, pos);
  else
    gemm_body<2>(As, Bs, A, Wv, Vt, nullptr, KVW, HIDN, row0, (bn - 40) * BN, pos);
}

__global__ __launch_bounds__(256) void gemm_out(
    const u16* __restrict__ A, const u16* __restrict__ B, float* __restrict__ C, int N, int K)
{
  __shared__ u16 As[BM * BK];
  __shared__ u16 Bs[BN * BK];
  gemm_body<3>(As, Bs, A, B, C, nullptr, N, K, blockIdx.y * BM, blockIdx.x * BN, nullptr);
}

// ---------------------------------------------------------------------------
// MFMA flash attention, 32x32 swapped-QK^T + balanced triangle pairing:
//  - grid 16 x NH; block p runs two 64-row q-tile phases {31-p, p}
//    -> exactly 33 key-tile iters per block (load-balanced).
//  - 4 waves split 2x2 over (row-half x key-half): each wave computes a
//    32x32 score block per 64-key tile via swapped QK^T = mfma(K,Q):
//    lane owns one q-row (col l31), softmax fully lane-local.
//  - P -> PV A-frag in registers via v_cvt_pk_bf16_f32 + v_permlane32_swap
//    (no P LDS round-trip).
//  - key-split requires one cross-wave O/lsum merge per phase through a
//    16KB LDS buffer (stride-1, conflict-free; 2x per block, negligible).
// ---------------------------------------------------------------------------
#define PAD 8
__global__ __launch_bounds__(256) void attn_mfma(
    const u16* __restrict__ Q, const u16* __restrict__ K, const u16* __restrict__ Kn,
    const u16* __restrict__ Vt, u16* __restrict__ O)
{
  __shared__ __align__(16) u16 Ks[64][HD + PAD];
  __shared__ __align__(16) u16 Kns[64][HD + PAD];
  __shared__ __align__(16) u16 Vts[HD][64 + PAD];
  __shared__ __align__(16) float Of[64][64];   // cross-wave O merge
  __shared__ float Lf[2][32];                  // cross-wave lsum merge
  __shared__ float Li[2][32];                  // per-row 1/l broadcast

  const int tid  = threadIdx.x;
  const int wave = tid >> 6;
  const int lane = tid & 63;
  const int l31  = lane & 31;
  const int hi   = lane >> 5;
  const int wr   = wave >> 1;                  // row half (0,1)
  const int wk   = wave & 1;                   // key half (0,1)
  const int h    = blockIdx.y;
  const int kh   = h >> 2;
  const int pr   = blockIdx.x;                 // pair index 0..15

  // staging map: 2 iters x 256 threads x 16B cover one 64x64 bf16 tile
  int sa[2], sb[2];
#pragma unroll
  for (int it = 0; it < 2; ++it) {
    const int u = it * 256 + tid;
    sa[it] = u >> 3;
    sb[it] = (u & 7) * 8;
  }

  for (int ph = 0; ph < 2; ++ph) {
    const int qt = ph ? pr : 31 - pr;          // heavy tile first
    const int i_base = qt * 64;
    const int rw0 = i_base + wr * 32;          // this wave's 32 q-rows
    const bool mixed_blk = (qt == 31);
    const bool mixed_wv  = mixed_blk && (rw0 + 31 >= CTX);

    // persistent Q B-frags: B[n=q=l31][k=d = i*16 + hi*8 + j]
    s16x8 bq[4];
#pragma unroll
    for (int i = 0; i < 4; ++i)
      bq[i] = *(const s16x8*)(Q + (size_t)(rw0 + l31) * HIDN + h * HD + i * 16 + hi * 8);

    f32x16 acc0 = {};      // O[q][d], d = l31       (rows in reg pattern)
    f32x16 acc1 = {};      // O[q][d], d = l31 + 32
    float lsum = 0.f;      // partial row sum (this lane's 16 keys)

    const int ntiles = qt + 1;
    s16x8 kr[2], vr[2], knr[2];
#pragma unroll
    for (int it = 0; it < 2; ++it) {
      kr[it] = *(const s16x8*)(K  + (size_t)sa[it] * KVW + kh * HD + sb[it]);
      vr[it] = *(const s16x8*)(Vt + (size_t)(kh * HD + sa[it]) * S_LEN + sb[it]);
      if (mixed_blk) knr[it] = *(const s16x8*)(Kn + (size_t)sa[it] * KVW + kh * HD + sb[it]);
    }

    for (int t = 0; t < ntiles; ++t) {
      const int jt = t * 64;
      __syncthreads();                        // LDS free (prev tile's reads done)
#pragma unroll
      for (int it = 0; it < 2; ++it) {
        *(s16x8*)&Ks[sa[it]][sb[it]]  = kr[it];
        *(s16x8*)&Vts[sa[it]][sb[it]] = vr[it];
        if (mixed_blk) *(s16x8*)&Kns[sa[it]][sb[it]] = knr[it];
      }
      __syncthreads();                        // LDS ready
      if (t + 1 < ntiles) {                   // prefetch next tile (overlaps compute)
        const int jn = jt + 64;
#pragma unroll
        for (int it = 0; it < 2; ++it) {
          kr[it] = *(const s16x8*)(K  + (size_t)(jn + sa[it]) * KVW + kh * HD + sb[it]);
          vr[it] = *(const s16x8*)(Vt + (size_t)(kh * HD + sa[it]) * S_LEN + jn + sb[it]);
          if (mixed_blk) knr[it] = *(const s16x8*)(Kn + (size_t)(jn + sa[it]) * KVW + kh * HD + sb[it]);
        }
      }

      const int j0 = jt + wk * 32;            // this wave's 32-key group
      if (j0 > rw0 + 31) continue;            // fully masked for this wave
      const bool needmask = (j0 + 31 > rw0);  // straddles the diagonal

      // swapped QK^T: D[m=key (reg pattern)][n=q (l31)]
      f32x16 sc = {};
#pragma unroll
      for (int i = 0; i < 4; ++i) {
        const s16x8 ak = *(const s16x8*)&Ks[wk * 32 + l31][i * 16 + hi * 8];
        sc = __builtin_amdgcn_mfma_f32_32x32x16_bf16(ak, bq[i], sc, 0, 0, 0);
      }
      if (mixed_wv) {                         // rows straddle CTX: also narrow scores
        f32x16 scn = {};
#pragma unroll
        for (int i = 0; i < 4; ++i) {
          const s16x8 ak = *(const s16x8*)&Kns[wk * 32 + l31][i * 16 + hi * 8];
          scn = __builtin_amdgcn_mfma_f32_32x32x16_bf16(ak, bq[i], scn, 0, 0, 0);
        }
        const bool nar = (rw0 + l31) >= CTX;  // per-lane: q-row selects rope
#pragma unroll
        for (int r = 0; r < 16; ++r) sc[r] = nar ? scn[r] : sc[r];
      }

      // lane-local softmax: p = exp2(min(s,80)) (Q pre-scaled by log2e/8)
      float p[16];
#pragma unroll
      for (int r = 0; r < 16; ++r) {
        float e = __builtin_amdgcn_exp2f(fminf(sc[r], 80.f));
        if (needmask) {
          const int key = j0 + (r & 3) + 8 * (r >> 2) + 4 * hi;
          e = (key > rw0 + l31) ? 0.f : e;
        }
        p[r] = e;
        lsum += e;
      }

      // pack p -> bf16 pairs: c[blk][j] = keys 8*blk + 4*hi + {2j, 2j+1}
      unsigned int c[4][2];
#pragma unroll
      for (int blk = 0; blk < 4; ++blk) {
        c[blk][0] = cvt_pk_bf16(p[4 * blk + 0], p[4 * blk + 1]);
        c[blk][1] = cvt_pk_bf16(p[4 * blk + 2], p[4 * blk + 3]);
      }

      // per 16-key slice s: swap halves -> A-frag words, then 2 PV MFMAs
#pragma unroll
      for (int s = 0; s < 2; ++s) {
        unsigned int w0 = c[2 * s][0], w2 = c[2 * s + 1][0];
        unsigned int w1 = c[2 * s][1], w3 = c[2 * s + 1][1];
        asm("v_permlane32_swap_b32 %0, %1" : "+v"(w0), "+v"(w2));
        asm("v_permlane32_swap_b32 %0, %1" : "+v"(w1), "+v"(w3));
        union { unsigned int u[4]; s16x8 v; } af;
        af.u[0] = w0; af.u[1] = w1; af.u[2] = w2; af.u[3] = w3;
        const int kc = wk * 32 + s * 16 + hi * 8;
        const s16x8 v0 = *(const s16x8*)&Vts[l31][kc];
        const s16x8 v1 = *(const s16x8*)&Vts[32 + l31][kc];
        acc0 = __builtin_amdgcn_mfma_f32_32x32x16_bf16(af.v, v0, acc0, 0, 0, 0);
        acc1 = __builtin_amdgcn_mfma_f32_32x32x16_bf16(af.v, v1, acc1, 0, 0, 0);
      }
    }

    // ---- cross-wave merge over key halves + epilogue (per phase) ----
    lsum += __shfl_xor(lsum, 32, 64);         // combine hi halves: row sum over
                                              // this wave's 32 keys, row = rw0+l31
    __syncthreads();                          // all compute done; LDS tiles free
    if (wk == 1) {
#pragma unroll
      for (int r = 0; r < 16; ++r) {
        const int rl = (r & 3) + 8 * (r >> 2) + 4 * hi;
        Of[wr * 32 + rl][l31]      = acc0[r];
        Of[wr * 32 + rl][l31 + 32] = acc1[r];
      }
      if (hi == 0) Lf[wr][l31] = lsum;
    }
    __syncthreads();
    if (wk == 0) {
      const float tot = lsum + Lf[wr][l31];
      const float inv = 1.0f / fmaxf(tot, 1e-30f);
      if (hi == 0) Li[wr][l31] = inv;         // same-wave write->read (in-order LDS)
#pragma unroll
      for (int r = 0; r < 16; ++r) {
        const int rl = (r & 3) + 8 * (r >> 2) + 4 * hi;
        const float iv = Li[wr][rl];
        const size_t o = (size_t)(rw0 + rl) * HIDN + h * HD + l31;
        O[o]      = f2bf((acc0[r] + Of[wr * 32 + rl][l31])      * iv);
        O[o + 32] = f2bf((acc1[r] + Of[wr * 32 + rl][l31 + 32]) * iv);
      }
    }
  }
}

// ---------------------------------------------------------------------------
extern "C" void kernel_launch(void* const* d_in, const int* in_sizes, int n_in,
                              void* d_out, int out_size, void* d_ws, size_t ws_size,
                              hipStream_t stream)
{
  const float* hidden = (const float*)d_in[0];
  const int* pos      = (const int*)d_in[2];   // d_in[1] mask: pure causal, unused
  const float* Wq = (const float*)d_in[3];
  const float* Wk = (const float*)d_in[4];
  const float* Wv = (const float*)d_in[5];
  const float* Wo = (const float*)d_in[6];
  float* out = (float*)d_out;

  char* ws = (char*)d_ws;
  u16* Qb  = (u16*)(ws);                    // 8 MB  bf16 Q (roped+scaled by gemm)
  u16* Kbb = (u16*)(ws + (8u  << 20));      // 2 MB  bf16 boost K (roped by gemm)
  u16* Knb = (u16*)(ws + (10u << 20));      // 2 MB  bf16 narrow K
  u16* Vtb = (u16*)(ws + (12u << 20));      // 2 MB  bf16 V transposed [kv_col][seq]
  u16* Ab  = (u16*)(ws + (14u << 20));      // 8 MB  bf16 attention output
  u16* Hb  = (u16*)(ws + (22u << 20));      // 8 MB  bf16 hidden
  u16* Wqb = (u16*)(ws + (30u << 20));      // 8 MB  bf16 Wq
  u16* Wkb = (u16*)(ws + (38u << 20));      // 2 MB  bf16 Wk
  u16* Wvb = (u16*)(ws + (40u << 20));      // 2 MB  bf16 Wv
  u16* Wob = (u16*)(ws + (42u << 20));      // 8 MB  bf16 Wo  => 50 MB total

  conv_all<<<dim3(14336), 256, 0, stream>>>(hidden, Wq, Wk, Wv, Wo, Hb, Wqb, Wkb, Wvb, Wob);
  gemm_qkv<<<dim3(48, 16), 256, 0, stream>>>(Hb, Wqb, Wkb, Wvb, Qb, Kbb, Knb, Vtb, pos);
  attn_mfma<<<dim3(16, NH), 256, 0, stream>>>(Qb, Kbb, Knb, Vtb, Ab);
  gemm_out<<<dim3(32, 16), 256, 0, stream>>>(Ab, Wob, out, HIDN, HIDN);
}